// Round 11
// baseline (316.706 us; speedup 1.0000x reference)
//
#include <hip/hip_runtime.h>

#define NN 8192
#define FIN 512
#define FOUT 256
#define JS 8
#define STRIP 1024
#define NSTEP 32

typedef _Float16 f16;
typedef __attribute__((ext_vector_type(8))) _Float16 f16x8;
typedef __attribute__((ext_vector_type(4))) _Float16 f16x4;
typedef __attribute__((ext_vector_type(4))) float f32x4;
typedef __attribute__((ext_vector_type(16))) float f32x16;
typedef __attribute__((ext_vector_type(4))) int i32x4;
typedef unsigned long long u64;

__device__ __forceinline__ float lrelu(float x) { return fmaxf(x, 0.2f * x); }

// ---- prep W: f32 [FIN][FOUT] -> f16 hi/lo transposed [FOUT][FIN]
__global__ void k_prep_w(const float* __restrict__ W, f16* __restrict__ wth,
                         f16* __restrict__ wtl) {
  int id = blockIdx.x * 256 + threadIdx.x;
  int c = id >> 9, k = id & 511;
  float v = W[k * FOUT + c];
  f16 a = (f16)v;
  wth[c * FIN + k] = a;
  wtl[c * FIN + k] = (f16)(v - (float)a);
}

// ---- GEMM1: Wh = h @ W via split-f16 MFMA; h converted to hi/lo in-reg.
// Emits whT16 (f16, tiled [j/16][256 c][16 j]), Wh1, Wh2 (f32).
__launch_bounds__(256, 2)
__global__ void k_gemm1(const float* __restrict__ h, const f16* __restrict__ wth,
                        const f16* __restrict__ wtl, const float* __restrict__ avec,
                        f16* __restrict__ whT16, float* __restrict__ wh1,
                        float* __restrict__ wh2) {
  int i0 = blockIdx.x * 32;
  int tid = threadIdx.x;
  int w = tid >> 6, l = tid & 63, m = l & 15, g = l >> 4;
  f32x4 acc[2][4] = {};
#pragma unroll 1
  for (int k0 = 0; k0 < FIN; k0 += 32) {
    f16x8 ah[2], al[2], bh[4], bl[4];
#pragma unroll
    for (int rf = 0; rf < 2; ++rf) {
      int ro = (i0 + 16 * rf + m) * FIN + k0 + 8 * g;
      f32x4 va = *(const f32x4*)(h + ro);
      f32x4 vb = *(const f32x4*)(h + ro + 4);
#pragma unroll
      for (int e = 0; e < 4; ++e) {
        f16 x = (f16)va[e];
        ah[rf][e] = x;
        al[rf][e] = (f16)(va[e] - (float)x);
        f16 y = (f16)vb[e];
        ah[rf][4 + e] = y;
        al[rf][4 + e] = (f16)(vb[e] - (float)y);
      }
    }
#pragma unroll
    for (int cf = 0; cf < 4; ++cf) {
      int co = (64 * w + 16 * cf + m) * FIN + k0 + 8 * g;
      bh[cf] = *(const f16x8*)(wth + co);
      bl[cf] = *(const f16x8*)(wtl + co);
    }
#pragma unroll
    for (int rf = 0; rf < 2; ++rf)
#pragma unroll
      for (int cf = 0; cf < 4; ++cf) {
        acc[rf][cf] = __builtin_amdgcn_mfma_f32_16x16x32_f16(ah[rf], bh[cf], acc[rf][cf], 0, 0, 0);
        acc[rf][cf] = __builtin_amdgcn_mfma_f32_16x16x32_f16(ah[rf], bl[cf], acc[rf][cf], 0, 0, 0);
        acc[rf][cf] = __builtin_amdgcn_mfma_f32_16x16x32_f16(al[rf], bh[cf], acc[rf][cf], 0, 0, 0);
      }
  }
  __shared__ float tile[32][FOUT + 1];
#pragma unroll
  for (int rf = 0; rf < 2; ++rf)
#pragma unroll
    for (int cf = 0; cf < 4; ++cf)
#pragma unroll
      for (int r = 0; r < 4; ++r)
        tile[16 * rf + 4 * g + r][64 * w + 16 * cf + m] = acc[rf][cf][r];
  __syncthreads();
  {  // whT16 tiled write: thread = column c, 32 rows = 2 j16-groups
    int c = tid;
    f16x8 vv[4];
#pragma unroll
    for (int r = 0; r < 32; ++r) vv[r >> 3][r & 7] = (f16)tile[r][c];
    size_t base = ((size_t)(i0 >> 4) * 256 + c) * 16;
    *(f16x8*)(whT16 + base) = vv[0];
    *(f16x8*)(whT16 + base + 8) = vv[1];
    *(f16x8*)(whT16 + base + 4096) = vv[2];
    *(f16x8*)(whT16 + base + 4096 + 8) = vv[3];
  }
  {  // Wh1/Wh2 row dots: 8 lanes per row
    int r = tid >> 3, ls = tid & 7;
    float s1 = 0.f, s2 = 0.f;
    for (int c = ls; c < FOUT; c += 8) {
      float v = tile[r][c];
      s1 = fmaf(v, avec[c], s1);
      s2 = fmaf(v, avec[FOUT + c], s2);
    }
#pragma unroll
    for (int off = 1; off < 8; off <<= 1) {
      s1 += __shfl_xor(s1, off);
      s2 += __shfl_xor(s2, off);
    }
    if (ls == 0) {
      wh1[i0 + r] = s1;
      wh2[i0 + r] = s2;
    }
  }
}

// ---- merged: global max of Wh2 + per-row/col exp factor tables.
__global__ void k_maxprep(const float* __restrict__ wh1, const float* __restrict__ wh2,
                          float* __restrict__ e1p, float* __restrict__ e1n,
                          float* __restrict__ thr, float* __restrict__ e2p,
                          float* __restrict__ e2n) {
  int t = threadIdx.x;
  float mx = -1e30f;
  for (int i = t; i < NN; i += 256) mx = fmaxf(mx, wh2[i]);
#pragma unroll
  for (int off = 1; off < 64; off <<= 1) mx = fmaxf(mx, __shfl_xor(mx, off));
  __shared__ float sm[4];
  if ((t & 63) == 0) sm[t >> 6] = mx;
  __syncthreads();
  float M2 = fmaxf(fmaxf(sm[0], sm[1]), fmaxf(sm[2], sm[3]));
  const float L = 1.4426950408889634f;
  int i = blockIdx.x * 256 + t;
  float w1 = wh1[i], w2 = wh2[i];
  float m = lrelu(w1 + M2);
  e1p[i] = exp2f((w1 - m) * L);
  e1n[i] = exp2f((0.2f * w1 - m) * L);
  thr[i] = exp2f(-w1 * L);
  e2p[i] = exp2f(w2 * L);
  e2n[i] = exp2f(0.2f * w2 * L);
}

// ---- fused mask-gen + masked-softmax + PV. adj is read DIRECTLY in the
// k-loop (no convert kernel): per step, lane l loads adj[2k+(l>>5)][jc+(l&31)]
// (16 coalesced loads, depth-2 prefetch), 16 ballots + lane-select give each
// lane its own row's 32 mask bits (bit j <-> j, linear). B staged via LDS
// (dbuf, XOR swizzle, one barrier/step). Wave = 32 rows x 256 cols x 1024-j.
// acc[8] f32x16 = 128 AGPR. Grid 64rb x 8js (XCD-affine strips).
__launch_bounds__(256, 2)
__global__ void k_attn(const int* __restrict__ adj, const f16* __restrict__ whT16,
                       const float* __restrict__ e1pA, const float* __restrict__ e1nA,
                       const float* __restrict__ thrA, const float* __restrict__ e2pA,
                       const float* __restrict__ e2nA, f16* __restrict__ accP,
                       float* __restrict__ zP) {
  int bx = blockIdx.x;
  int js = bx & (JS - 1), rb = bx >> 3;
  int i0b = rb * 128;
  int jbase = js * STRIP;
  int tid = threadIdx.x, w = tid >> 6, l = tid & 63;
  int lr = l & 31, hi = l >> 5;
  int row = i0b + w * 32 + lr;

  __shared__ __align__(16) char ldsB[2][16384];

  float E1p = e1pA[row], E1n = e1nA[row], T = thrA[row];
  f32x16 acc[8] = {};
  float za = 0.f;

  const f16* bStrip = whT16 + (size_t)(jbase >> 4) * 4096;
  const float* e2pb = e2pA + jbase + 8 * hi;
  const float* e2nb = e2nA + jbase + 8 * hi;

  // adj lane source: row-pair loads — load k covers rows {2k, 2k+1},
  // lanes 0..31 -> row 2k (j = jc + lane), lanes 32..63 -> row 2k+1.
  const int* aSrc = adj + (size_t)(i0b + 32 * w + (l >> 5)) * NN + jbase + (l & 31);

  // B staging map (R9): granule g (16B) -> src 8g f16; LDS XOR-swizzled
  int ldst[4];
  size_t gsrc[4];
#pragma unroll
  for (int r = 0; r < 4; ++r) {
    int g = r * 256 + tid;
    gsrc[r] = (size_t)(g >> 9) * 4096 + 8 * (g & 511);
    ldst[r] = (g >> 9) * 8192 + ((16 * (g & 511)) ^ (((g >> 3) & 7) << 4));
  }
  int rdbase = (lr * 32 + hi * 16) ^ (((lr >> 2) & 7) << 4);

  i32x4 stg[4];
  // prologue: stage B(0); prefetch adj steps 0 and 1
#pragma unroll
  for (int r = 0; r < 4; ++r)
    stg[r] = __builtin_nontemporal_load((const i32x4*)(whT16 + (size_t)(jbase >> 4) * 4096 + gsrc[r]));
#pragma unroll
  for (int r = 0; r < 4; ++r) *(i32x4*)(&ldsB[0][ldst[r]]) = stg[r];

  int pre[2][16];
#pragma unroll
  for (int k = 0; k < 16; ++k) {
    pre[0][k] = __builtin_nontemporal_load(aSrc + (size_t)(2 * k) * NN);
    pre[1][k] = __builtin_nontemporal_load(aSrc + (size_t)(2 * k) * NN + 32);
  }
  __syncthreads();

#pragma unroll 1
  for (int t = 0; t < NSTEP; ++t) {
    int cur = t & 1;
    int jc = t * 32;
    // masks for step t: ballot per row-pair, select own row's 32 bits
    unsigned b32 = 0;
#pragma unroll
    for (int k = 0; k < 16; ++k) {
      u64 b = __ballot(pre[cur][k] > 0);
      unsigned mine = (lr & 1) ? (unsigned)(b >> 32) : (unsigned)b;
      if ((lr >> 1) == k) b32 = mine;
    }
    // issue adj loads for step t+2 into the freed bank
    if (t + 2 < NSTEP) {
#pragma unroll
      for (int k = 0; k < 16; ++k)
        pre[cur][k] =
            __builtin_nontemporal_load(aSrc + (size_t)(2 * k) * NN + (t + 2) * 32);
    }
    // issue B(t+1) global loads (hide under genP + MFMA)
    if (t + 1 < NSTEP) {
      const f16* src = bStrip + (size_t)(t + 1) * 8192;
#pragma unroll
      for (int r = 0; r < 4; ++r)
        stg[r] = __builtin_nontemporal_load((const i32x4*)(src + gsrc[r]));
    }
    // genP: element (kb, f) <-> j = jc + 16*kb + 8*hi + f <-> bit 16*kb+8*hi+f
    unsigned bits0 = (b32 >> (8 * hi)) & 0xFFu;
    unsigned bits1 = (b32 >> (16 + 8 * hi)) & 0xFFu;
    f16x8 pa0, pa1;
#pragma unroll
    for (int q = 0; q < 2; ++q) {
      int fo = jc + 4 * q;
      f32x4 ep0 = *(const f32x4*)(e2pb + fo);
      f32x4 en0 = *(const f32x4*)(e2nb + fo);
      f32x4 ep1 = *(const f32x4*)(e2pb + fo + 16);
      f32x4 en1 = *(const f32x4*)(e2nb + fo + 16);
#pragma unroll
      for (int e = 0; e < 4; ++e) {
        int f = 4 * q + e;
        bool s0 = ep0[e] >= T;
        float v0 = (s0 ? E1p : E1n) * (s0 ? ep0[e] : en0[e]);
        v0 = ((bits0 >> f) & 1u) ? v0 : 0.f;
        za += v0;
        pa0[f] = (f16)v0;
        bool s1 = ep1[e] >= T;
        float v1 = (s1 ? E1p : E1n) * (s1 ? ep1[e] : en1[e]);
        v1 = ((bits1 >> f) & 1u) ? v1 : 0.f;
        za += v1;
        pa1[f] = (f16)v1;
      }
    }
    // MFMA from LDS (conflict-free swizzled reads)
#pragma unroll
    for (int cf = 0; cf < 8; ++cf) {
      f16x8 bf0 = *(const f16x8*)(&ldsB[cur][cf * 1024 + rdbase]);
      acc[cf] = __builtin_amdgcn_mfma_f32_32x32x16_f16(pa0, bf0, acc[cf], 0, 0, 0);
    }
#pragma unroll
    for (int cf = 0; cf < 8; ++cf) {
      f16x8 bf1 = *(const f16x8*)(&ldsB[cur][8192 + cf * 1024 + rdbase]);
      acc[cf] = __builtin_amdgcn_mfma_f32_32x32x16_f16(pa1, bf1, acc[cf], 0, 0, 0);
    }
    // write B(t+1) into the other buffer, one barrier per step
    if (t + 1 < NSTEP) {
#pragma unroll
      for (int r = 0; r < 4; ++r) *(i32x4*)(&ldsB[cur ^ 1][ldst[r]]) = stg[r];
      __syncthreads();
    }
  }

  // Z: hi=0/1 lanes hold complementary j-slots of row
  za += __shfl_xor(za, 32);
  if (hi == 0) zP[(size_t)js * NN + row] = za;

  // partial accumulator out, f16 NT. C/D: col=lane&31, row=(r&3)+8*(r>>2)+4*hi
  f16* ap = accP + (size_t)js * NN * FOUT;
#pragma unroll
  for (int c = 0; c < 8; ++c)
#pragma unroll
    for (int r = 0; r < 16; ++r) {
      int grow = i0b + 32 * w + (r & 3) + 8 * (r >> 2) + 4 * hi;
      int gcol = c * 32 + lr;
      __builtin_nontemporal_store((f16)acc[c][r], ap + (size_t)grow * FOUT + gcol);
    }
}

// ---- combine JS f16 partials, divide by Z, elu
__global__ void k_combine(const f16* __restrict__ accP, const float* __restrict__ zP,
                          float* __restrict__ out) {
  int id = blockIdx.x * 256 + threadIdx.x;
  size_t idx = (size_t)id * 4;
  int row = (int)(idx >> 8);
  f32x4 s = {};
#pragma unroll
  for (int p = 0; p < JS; ++p) {
    f16x4 v = *(const f16x4*)(accP + (size_t)p * NN * FOUT + idx);
#pragma unroll
    for (int i = 0; i < 4; ++i) s[i] += (float)v[i];
  }
  float z = 0.f;
#pragma unroll
  for (int p = 0; p < JS; ++p) z += zP[(size_t)p * NN + row];
  float inv = (z > 0.f) ? 1.f / z : 0.f;
  f32x4 o;
#pragma unroll
  for (int i = 0; i < 4; ++i) {
    float x = s[i] * inv;
    o[i] = (x > 0.f) ? x : expm1f(x);
  }
  *(f32x4*)(out + idx) = o;
}

extern "C" void kernel_launch(void* const* d_in, const int* in_sizes, int n_in,
                              void* d_out, int out_size, void* d_ws, size_t ws_size,
                              hipStream_t stream) {
  const float* h = (const float*)d_in[0];
  const int* adj = (const int*)d_in[1];
  const float* W = (const float*)d_in[2];
  const float* a = (const float*)d_in[3];
  (void)in_sizes; (void)n_in; (void)out_size; (void)ws_size;

  char* ws = (char*)d_ws;
  size_t off = 0;
  auto alloc = [&](size_t bytes) {
    void* p = ws + off;
    off = (off + bytes + 255) & ~(size_t)255;
    return p;
  };
  f16* accP = (f16*)alloc((size_t)JS * NN * FOUT * 2);  // 32 MB
  f16* whT16 = (f16*)alloc((size_t)FOUT * NN * 2);      // 4 MB
  f16* wth = (f16*)alloc((size_t)FOUT * FIN * 2);
  f16* wtl = (f16*)alloc((size_t)FOUT * FIN * 2);
  float* wh1 = (float*)alloc((size_t)NN * 4);
  float* wh2 = (float*)alloc((size_t)NN * 4);
  float* e1p = (float*)alloc((size_t)NN * 4);
  float* e1n = (float*)alloc((size_t)NN * 4);
  float* thr = (float*)alloc((size_t)NN * 4);
  float* e2p = (float*)alloc((size_t)NN * 4);
  float* e2n = (float*)alloc((size_t)NN * 4);
  float* zP = (float*)alloc((size_t)JS * NN * 4);

  k_prep_w<<<FIN * FOUT / 256, 256, 0, stream>>>(W, wth, wtl);
  k_gemm1<<<NN / 32, 256, 0, stream>>>(h, wth, wtl, a, whT16, wh1, wh2);
  k_maxprep<<<NN / 256, 256, 0, stream>>>(wh1, wh2, e1p, e1n, thr, e2p, e2n);
  k_attn<<<(NN / 128) * JS, 256, 0, stream>>>(adj, whT16, e1p, e1n, thr, e2p, e2n,
                                              accP, zP);
  k_combine<<<NN * FOUT / 1024, 256, 0, stream>>>(accP, zP, (float*)d_out);
}

// Round 12
// 206.248 us; speedup vs baseline: 1.5356x; 1.5356x over previous
//
#include <hip/hip_runtime.h>

#define NN 8192
#define FIN 512
#define FOUT 256
#define JS 8
#define STRIP 1024
#define NSTEP 32

typedef _Float16 f16;
typedef __attribute__((ext_vector_type(8))) _Float16 f16x8;
typedef __attribute__((ext_vector_type(4))) _Float16 f16x4;
typedef __attribute__((ext_vector_type(4))) float f32x4;
typedef __attribute__((ext_vector_type(16))) float f32x16;
typedef __attribute__((ext_vector_type(4))) int i32x4;
typedef unsigned long long u64;

__device__ __forceinline__ float lrelu(float x) { return fmaxf(x, 0.2f * x); }

// ---- prep W: f32 [FIN][FOUT] -> f16 hi/lo transposed [FOUT][FIN]
__global__ void k_prep_w(const float* __restrict__ W, f16* __restrict__ wth,
                         f16* __restrict__ wtl) {
  int id = blockIdx.x * 256 + threadIdx.x;
  int c = id >> 9, k = id & 511;
  float v = W[k * FOUT + c];
  f16 a = (f16)v;
  wth[c * FIN + k] = a;
  wtl[c * FIN + k] = (f16)(v - (float)a);
}

// ---- GEMM1: Wh = h @ W via split-f16 MFMA; h converted to hi/lo in-reg.
// Emits whT16 (f16, tiled [j/16][256 c][16 j]), Wh1, Wh2 (f32).
__launch_bounds__(256, 2)
__global__ void k_gemm1(const float* __restrict__ h, const f16* __restrict__ wth,
                        const f16* __restrict__ wtl, const float* __restrict__ avec,
                        f16* __restrict__ whT16, float* __restrict__ wh1,
                        float* __restrict__ wh2) {
  int i0 = blockIdx.x * 32;
  int tid = threadIdx.x;
  int w = tid >> 6, l = tid & 63, m = l & 15, g = l >> 4;
  f32x4 acc[2][4] = {};
#pragma unroll 1
  for (int k0 = 0; k0 < FIN; k0 += 32) {
    f16x8 ah[2], al[2], bh[4], bl[4];
#pragma unroll
    for (int rf = 0; rf < 2; ++rf) {
      int ro = (i0 + 16 * rf + m) * FIN + k0 + 8 * g;
      f32x4 va = *(const f32x4*)(h + ro);
      f32x4 vb = *(const f32x4*)(h + ro + 4);
#pragma unroll
      for (int e = 0; e < 4; ++e) {
        f16 x = (f16)va[e];
        ah[rf][e] = x;
        al[rf][e] = (f16)(va[e] - (float)x);
        f16 y = (f16)vb[e];
        ah[rf][4 + e] = y;
        al[rf][4 + e] = (f16)(vb[e] - (float)y);
      }
    }
#pragma unroll
    for (int cf = 0; cf < 4; ++cf) {
      int co = (64 * w + 16 * cf + m) * FIN + k0 + 8 * g;
      bh[cf] = *(const f16x8*)(wth + co);
      bl[cf] = *(const f16x8*)(wtl + co);
    }
#pragma unroll
    for (int rf = 0; rf < 2; ++rf)
#pragma unroll
      for (int cf = 0; cf < 4; ++cf) {
        acc[rf][cf] = __builtin_amdgcn_mfma_f32_16x16x32_f16(ah[rf], bh[cf], acc[rf][cf], 0, 0, 0);
        acc[rf][cf] = __builtin_amdgcn_mfma_f32_16x16x32_f16(ah[rf], bl[cf], acc[rf][cf], 0, 0, 0);
        acc[rf][cf] = __builtin_amdgcn_mfma_f32_16x16x32_f16(al[rf], bh[cf], acc[rf][cf], 0, 0, 0);
      }
  }
  __shared__ float tile[32][FOUT + 1];
#pragma unroll
  for (int rf = 0; rf < 2; ++rf)
#pragma unroll
    for (int cf = 0; cf < 4; ++cf)
#pragma unroll
      for (int r = 0; r < 4; ++r)
        tile[16 * rf + 4 * g + r][64 * w + 16 * cf + m] = acc[rf][cf][r];
  __syncthreads();
  {  // whT16 tiled write: thread = column c, 32 rows = 2 j16-groups
    int c = tid;
    f16x8 vv[4];
#pragma unroll
    for (int r = 0; r < 32; ++r) vv[r >> 3][r & 7] = (f16)tile[r][c];
    size_t base = ((size_t)(i0 >> 4) * 256 + c) * 16;
    *(f16x8*)(whT16 + base) = vv[0];
    *(f16x8*)(whT16 + base + 8) = vv[1];
    *(f16x8*)(whT16 + base + 4096) = vv[2];
    *(f16x8*)(whT16 + base + 4096 + 8) = vv[3];
  }
  {  // Wh1/Wh2 row dots: 8 lanes per row
    int r = tid >> 3, ls = tid & 7;
    float s1 = 0.f, s2 = 0.f;
    for (int c = ls; c < FOUT; c += 8) {
      float v = tile[r][c];
      s1 = fmaf(v, avec[c], s1);
      s2 = fmaf(v, avec[FOUT + c], s2);
    }
#pragma unroll
    for (int off = 1; off < 8; off <<= 1) {
      s1 += __shfl_xor(s1, off);
      s2 += __shfl_xor(s2, off);
    }
    if (ls == 0) {
      wh1[i0 + r] = s1;
      wh2[i0 + r] = s2;
    }
  }
}

// ---- merged: global max of Wh2 + per-row/per-col exp factor tables.
__global__ void k_maxprep(const float* __restrict__ wh1, const float* __restrict__ wh2,
                          float* __restrict__ e1p, float* __restrict__ e1n,
                          float* __restrict__ thr, float* __restrict__ e2p,
                          float* __restrict__ e2n) {
  int t = threadIdx.x;
  float mx = -1e30f;
  for (int i = t; i < NN; i += 256) mx = fmaxf(mx, wh2[i]);
#pragma unroll
  for (int off = 1; off < 64; off <<= 1) mx = fmaxf(mx, __shfl_xor(mx, off));
  __shared__ float sm[4];
  if ((t & 63) == 0) sm[t >> 6] = mx;
  __syncthreads();
  float M2 = fmaxf(fmaxf(sm[0], sm[1]), fmaxf(sm[2], sm[3]));
  const float L = 1.4426950408889634f;
  int i = blockIdx.x * 256 + t;
  float w1 = wh1[i], w2 = wh2[i];
  float m = lrelu(w1 + M2);
  e1p[i] = exp2f((w1 - m) * L);
  e1n[i] = exp2f((0.2f * w1 - m) * L);
  thr[i] = exp2f(-w1 * L);
  e2p[i] = exp2f(w2 * L);
  e2n[i] = exp2f(0.2f * w2 * L);
}

// ---- fully-fused adj-read + masked-softmax + PV. BARRIER-FREE (the R11
// lesson: any per-step __syncthreads drains vmcnt(0) and kills the adj
// prefetch). Wave = 32 rows x 256 cols x 1024-j strip, fully independent.
// adj staged coalesced (4 nt-load instrs/step, 8x128B segments each) into a
// wave-private 4KB LDS tile (R5's XOR-swizzle transpose, in-order DS);
// reg prefetch issued ~2 steps ahead. genP exp-free from tables. B read
// directly from L2-hot whT16 (kb0 issued first-in-step, covered by genP;
// kb1 covered by kb0's MFMAs). acc[8] f32x16 = 128 AGPR.
// Grid 64rb x 8js (js = bx&7 -> XCD-affine strip).
__launch_bounds__(256, 2)
__global__ void k_attn(const int* __restrict__ adj, const f16* __restrict__ whT16,
                       const float* __restrict__ e1pA, const float* __restrict__ e1nA,
                       const float* __restrict__ thrA, const float* __restrict__ e2pA,
                       const float* __restrict__ e2nA, f16* __restrict__ accP,
                       float* __restrict__ zP) {
  int bx = blockIdx.x;
  int js = bx & (JS - 1), rb = bx >> 3;
  int i0b = rb * 128;
  int jbase = js * STRIP;
  int tid = threadIdx.x, w = tid >> 6, l = tid & 63;
  int lr = l & 31, hi = l >> 5;
  int i0w = i0b + w * 32;
  int row = i0w + lr;

  __shared__ int adjT[4][32 * 32];  // wave-private [32 rows][32 ints], swizzled
  int* aW = adjT[w];

  float E1p = e1pA[row], E1n = e1nA[row], T = thrA[row];
  f32x16 acc[8] = {};
  float za = 0.f;

  // adj stage identity: lane covers (rows 8q+ldr, granule ldc of 4 ints)
  int ldr = l >> 3, ldc = l & 7;
  const int* aSrc = adj + (size_t)(i0w + ldr) * NN + jbase + ldc * 4;
  int wbase = ldr * 32 + (ldc ^ ldr) * 4;  // write slot, key = row&7
  // transposed read: row lr, granules q = 2hi + {0,1,4,5}
  int rq[4];
#pragma unroll
  for (int qi = 0; qi < 4; ++qi) {
    int q = 2 * hi + 4 * (qi >> 1) + (qi & 1);
    rq[qi] = lr * 32 + (q ^ (lr & 7)) * 4;
  }

  const f16* bPB = whT16 + (size_t)(jbase >> 4) * 4096 + (size_t)lr * 16 + hi * 8;
  const float* e2pb = e2pA + jbase + 8 * hi;
  const float* e2nb = e2nA + jbase + 8 * hi;

  // prologue: stage adj(0) to LDS; banks: R[t&1] holds step-t data
  i32x4 R[2][4];
#pragma unroll
  for (int q = 0; q < 4; ++q)
    R[0][q] = __builtin_nontemporal_load((const i32x4*)(aSrc + (size_t)8 * q * NN));
#pragma unroll
  for (int q = 0; q < 4; ++q)
    R[1][q] = __builtin_nontemporal_load((const i32x4*)(aSrc + (size_t)8 * q * NN + 32));
#pragma unroll
  for (int q = 0; q < 4; ++q) *(i32x4*)(aW + wbase + q * 256) = R[0][q];
#pragma unroll
  for (int q = 0; q < 4; ++q)
    R[0][q] = __builtin_nontemporal_load((const i32x4*)(aSrc + (size_t)8 * q * NN + 64));

  f16x8 bf[8];

#pragma unroll 1
  for (int t = 0; t < NSTEP; ++t) {
    int jc = t * 32;
    // issue B(t, kb0) first — genP below covers the L2 latency
    {
      const f16* bt = bPB + (size_t)(2 * t) * 4096;
#pragma unroll
      for (int c = 0; c < 8; ++c) bf[c] = *(const f16x8*)(bt + c * 512);
    }
    // read this step's adj ints from LDS (in-order DS, no barrier)
    i32x4 av[4];
#pragma unroll
    for (int qi = 0; qi < 4; ++qi) av[qi] = *(const i32x4*)(aW + rq[qi]);
    // write adj(t+1) into LDS; issue adj(t+3) into the freed bank
    if (t + 1 < NSTEP) {
      int p = (t + 1) & 1;
#pragma unroll
      for (int q = 0; q < 4; ++q) *(i32x4*)(aW + wbase + q * 256) = R[p][q];
      int tl = (t + 3 < NSTEP) ? t + 3 : NSTEP - 1;
#pragma unroll
      for (int q = 0; q < 4; ++q)
        R[p][q] = __builtin_nontemporal_load(
            (const i32x4*)(aSrc + (size_t)8 * q * NN + 32 * tl));
    }
    // genP: av[qi][e] <-> j = jc + 16*(qi>>1) + 8*hi + 4*(qi&1) + e
    f16x8 pa0, pa1;
#pragma unroll
    for (int qi = 0; qi < 4; ++qi) {
      int fo = jc + 16 * (qi >> 1) + 4 * (qi & 1);
      f32x4 ep = *(const f32x4*)(e2pb + fo);
      f32x4 en = *(const f32x4*)(e2nb + fo);
#pragma unroll
      for (int e = 0; e < 4; ++e) {
        bool s = ep[e] >= T;
        float v = (s ? E1p : E1n) * (s ? ep[e] : en[e]);
        v = (av[qi][e] > 0) ? v : 0.f;
        za += v;
        if (qi < 2)
          pa0[(qi & 1) * 4 + e] = (f16)v;
        else
          pa1[(qi & 1) * 4 + e] = (f16)v;
      }
    }
    // MFMA kb0 (bf loaded at step start)
#pragma unroll
    for (int c = 0; c < 8; ++c)
      acc[c] = __builtin_amdgcn_mfma_f32_32x32x16_f16(pa0, bf[c], acc[c], 0, 0, 0);
    // issue + consume B(t, kb1): loads covered by kb0's 8 MFMAs (~256 cy)
    {
      const f16* bt = bPB + (size_t)(2 * t + 1) * 4096;
#pragma unroll
      for (int c = 0; c < 8; ++c) bf[c] = *(const f16x8*)(bt + c * 512);
    }
#pragma unroll
    for (int c = 0; c < 8; ++c)
      acc[c] = __builtin_amdgcn_mfma_f32_32x32x16_f16(pa1, bf[c], acc[c], 0, 0, 0);
  }

  // Z: hi=0/1 lanes hold complementary j-slots of row
  za += __shfl_xor(za, 32);
  if (hi == 0) zP[(size_t)js * NN + row] = za;

  // partial accumulator out, f16 NT. C/D: col=lane&31, row=(r&3)+8*(r>>2)+4*hi
  f16* ap = accP + (size_t)js * NN * FOUT;
#pragma unroll
  for (int c = 0; c < 8; ++c)
#pragma unroll
    for (int r = 0; r < 16; ++r) {
      int grow = i0b + 32 * w + (r & 3) + 8 * (r >> 2) + 4 * hi;
      int gcol = c * 32 + lr;
      __builtin_nontemporal_store((f16)acc[c][r], ap + (size_t)grow * FOUT + gcol);
    }
}

// ---- combine JS f16 partials, divide by Z, elu
__global__ void k_combine(const f16* __restrict__ accP, const float* __restrict__ zP,
                          float* __restrict__ out) {
  int id = blockIdx.x * 256 + threadIdx.x;
  size_t idx = (size_t)id * 4;
  int row = (int)(idx >> 8);
  f32x4 s = {};
#pragma unroll
  for (int p = 0; p < JS; ++p) {
    f16x4 v = *(const f16x4*)(accP + (size_t)p * NN * FOUT + idx);
#pragma unroll
    for (int i = 0; i < 4; ++i) s[i] += (float)v[i];
  }
  float z = 0.f;
#pragma unroll
  for (int p = 0; p < JS; ++p) z += zP[(size_t)p * NN + row];
  float inv = (z > 0.f) ? 1.f / z : 0.f;
  f32x4 o;
#pragma unroll
  for (int i = 0; i < 4; ++i) {
    float x = s[i] * inv;
    o[i] = (x > 0.f) ? x : expm1f(x);
  }
  *(f32x4*)(out + idx) = o;
}

extern "C" void kernel_launch(void* const* d_in, const int* in_sizes, int n_in,
                              void* d_out, int out_size, void* d_ws, size_t ws_size,
                              hipStream_t stream) {
  const float* h = (const float*)d_in[0];
  const int* adj = (const int*)d_in[1];
  const float* W = (const float*)d_in[2];
  const float* a = (const float*)d_in[3];
  (void)in_sizes; (void)n_in; (void)out_size; (void)ws_size;

  char* ws = (char*)d_ws;
  size_t off = 0;
  auto alloc = [&](size_t bytes) {
    void* p = ws + off;
    off = (off + bytes + 255) & ~(size_t)255;
    return p;
  };
  f16* accP = (f16*)alloc((size_t)JS * NN * FOUT * 2);  // 32 MB
  f16* whT16 = (f16*)alloc((size_t)FOUT * NN * 2);      // 4 MB
  f16* wth = (f16*)alloc((size_t)FOUT * FIN * 2);
  f16* wtl = (f16*)alloc((size_t)FOUT * FIN * 2);
  float* wh1 = (float*)alloc((size_t)NN * 4);
  float* wh2 = (float*)alloc((size_t)NN * 4);
  float* e1p = (float*)alloc((size_t)NN * 4);
  float* e1n = (float*)alloc((size_t)NN * 4);
  float* thr = (float*)alloc((size_t)NN * 4);
  float* e2p = (float*)alloc((size_t)NN * 4);
  float* e2n = (float*)alloc((size_t)NN * 4);
  float* zP = (float*)alloc((size_t)JS * NN * 4);

  k_prep_w<<<FIN * FOUT / 256, 256, 0, stream>>>(W, wth, wtl);
  k_gemm1<<<NN / 32, 256, 0, stream>>>(h, wth, wtl, a, whT16, wh1, wh2);
  k_maxprep<<<NN / 256, 256, 0, stream>>>(wh1, wh2, e1p, e1n, thr, e2p, e2n);
  k_attn<<<(NN / 128) * JS, 256, 0, stream>>>(adj, whT16, e1p, e1n, thr, e2p, e2n,
                                              accP, zP);
  k_combine<<<NN * FOUT / 1024, 256, 0, stream>>>(accP, zP, (float*)d_out);
}

// Round 13
// 183.587 us; speedup vs baseline: 1.7251x; 1.1234x over previous
//
#include <hip/hip_runtime.h>

#define NN 8192
#define FIN 512
#define FOUT 256
#define JS 8
#define STRIP 1024
#define NSTEP 32

typedef _Float16 f16;
typedef __attribute__((ext_vector_type(8))) _Float16 f16x8;
typedef __attribute__((ext_vector_type(4))) _Float16 f16x4;
typedef __attribute__((ext_vector_type(4))) float f32x4;
typedef __attribute__((ext_vector_type(16))) float f32x16;
typedef __attribute__((ext_vector_type(4))) int i32x4;
typedef unsigned long long u64;

__device__ __forceinline__ float lrelu(float x) { return fmaxf(x, 0.2f * x); }

// ---- prep W: f32 [FIN][FOUT] -> f16 hi/lo transposed [FOUT][FIN]
__global__ void k_prep_w(const float* __restrict__ W, f16* __restrict__ wth,
                         f16* __restrict__ wtl) {
  int id = blockIdx.x * 256 + threadIdx.x;
  int c = id >> 9, k = id & 511;
  float v = W[k * FOUT + c];
  f16 a = (f16)v;
  wth[c * FIN + k] = a;
  wtl[c * FIN + k] = (f16)(v - (float)a);
}

// ---- HETERO: blocks [0, NN/32) run the R9 gemm1 body (32-row split-f16
// tiles); blocks [NN/32, NN/32+NN/4) run the R9 depth-4 ballot convert
// (wave = one adj row). Both inner loops are byte-identical to the proven
// R9 kernels — the fusion only buys co-residency: gemm's MFMA work hides
// under the HBM-bound adj stream instead of serializing after it.
__launch_bounds__(256, 2)
__global__ void k_fused(const int* __restrict__ adj, u64* __restrict__ maskG,
                        const float* __restrict__ h, const f16* __restrict__ wth,
                        const f16* __restrict__ wtl, const float* __restrict__ avec,
                        f16* __restrict__ whT16, float* __restrict__ wh1,
                        float* __restrict__ wh2) {
  int bid = blockIdx.x;
  int tid = threadIdx.x;
  __shared__ float tile[32][FOUT + 1];
  if (bid < NN / 32) {
    // ---------------- gemm1 (R9 verbatim): Wh = h @ W via split-f16 MFMA
    int i0 = bid * 32;
    int w = tid >> 6, l = tid & 63, m = l & 15, g = l >> 4;
    f32x4 acc[2][4] = {};
#pragma unroll 1
    for (int k0 = 0; k0 < FIN; k0 += 32) {
      f16x8 ah[2], al[2], bh[4], bl[4];
#pragma unroll
      for (int rf = 0; rf < 2; ++rf) {
        int ro = (i0 + 16 * rf + m) * FIN + k0 + 8 * g;
        f32x4 va = *(const f32x4*)(h + ro);
        f32x4 vb = *(const f32x4*)(h + ro + 4);
#pragma unroll
        for (int e = 0; e < 4; ++e) {
          f16 x = (f16)va[e];
          ah[rf][e] = x;
          al[rf][e] = (f16)(va[e] - (float)x);
          f16 y = (f16)vb[e];
          ah[rf][4 + e] = y;
          al[rf][4 + e] = (f16)(vb[e] - (float)y);
        }
      }
#pragma unroll
      for (int cf = 0; cf < 4; ++cf) {
        int co = (64 * w + 16 * cf + m) * FIN + k0 + 8 * g;
        bh[cf] = *(const f16x8*)(wth + co);
        bl[cf] = *(const f16x8*)(wtl + co);
      }
#pragma unroll
      for (int rf = 0; rf < 2; ++rf)
#pragma unroll
        for (int cf = 0; cf < 4; ++cf) {
          acc[rf][cf] = __builtin_amdgcn_mfma_f32_16x16x32_f16(ah[rf], bh[cf], acc[rf][cf], 0, 0, 0);
          acc[rf][cf] = __builtin_amdgcn_mfma_f32_16x16x32_f16(ah[rf], bl[cf], acc[rf][cf], 0, 0, 0);
          acc[rf][cf] = __builtin_amdgcn_mfma_f32_16x16x32_f16(al[rf], bh[cf], acc[rf][cf], 0, 0, 0);
        }
    }
#pragma unroll
    for (int rf = 0; rf < 2; ++rf)
#pragma unroll
      for (int cf = 0; cf < 4; ++cf)
#pragma unroll
        for (int r = 0; r < 4; ++r)
          tile[16 * rf + 4 * g + r][64 * w + 16 * cf + m] = acc[rf][cf][r];
    __syncthreads();
    {  // whT16 tiled write: thread = column c, 32 rows = 2 j16-groups
      int c = tid;
      f16x8 vv[4];
#pragma unroll
      for (int r = 0; r < 32; ++r) vv[r >> 3][r & 7] = (f16)tile[r][c];
      size_t base = ((size_t)(i0 >> 4) * 256 + c) * 16;
      *(f16x8*)(whT16 + base) = vv[0];
      *(f16x8*)(whT16 + base + 8) = vv[1];
      *(f16x8*)(whT16 + base + 4096) = vv[2];
      *(f16x8*)(whT16 + base + 4096 + 8) = vv[3];
    }
    {  // Wh1/Wh2 row dots: 8 lanes per row
      int r = tid >> 3, ls = tid & 7;
      float s1 = 0.f, s2 = 0.f;
      for (int c = ls; c < FOUT; c += 8) {
        float v = tile[r][c];
        s1 = fmaf(v, avec[c], s1);
        s2 = fmaf(v, avec[FOUT + c], s2);
      }
#pragma unroll
      for (int off = 1; off < 8; off <<= 1) {
        s1 += __shfl_xor(s1, off);
        s2 += __shfl_xor(s2, off);
      }
      if (ls == 0) {
        wh1[i0 + r] = s1;
        wh2[i0 + r] = s2;
      }
    }
  } else {
    // ---------------- convert (R9 verbatim): adj row -> bitmask via ballot,
    // depth-4 reg prefetch. bit l of word (row*128 + p*4 + e) <-> j = p*256+4l+e
    int gw = (bid - NN / 32) * 4 + (tid >> 6);
    int l = tid & 63;
    const int* src = adj + (size_t)gw * NN + 4 * l;
    u64* dst = maskG + (size_t)gw * 128;
    i32x4 v[4];
#pragma unroll
    for (int p = 0; p < 4; ++p)
      v[p] = __builtin_nontemporal_load((const i32x4*)(src + p * 256));
#pragma unroll 1
    for (int p = 0; p < 32; ++p) {
      i32x4 cur = v[p & 3];
      u64 b0 = __ballot(cur[0] > 0);
      u64 b1 = __ballot(cur[1] > 0);
      u64 b2 = __ballot(cur[2] > 0);
      u64 b3 = __ballot(cur[3] > 0);
      if (p + 4 < 32)
        v[p & 3] = __builtin_nontemporal_load((const i32x4*)(src + (p + 4) * 256));
      if (l < 4) {
        u64 bb = (l == 0) ? b0 : (l == 1) ? b1 : (l == 2) ? b2 : b3;
        dst[p * 4 + l] = bb;
      }
    }
  }
}

// ---- merged: global max of Wh2 + per-row/per-col exp factor tables.
__global__ void k_maxprep(const float* __restrict__ wh1, const float* __restrict__ wh2,
                          float* __restrict__ e1p, float* __restrict__ e1n,
                          float* __restrict__ thr, float* __restrict__ e2p,
                          float* __restrict__ e2n) {
  int t = threadIdx.x;
  float mx = -1e30f;
  for (int i = t; i < NN; i += 256) mx = fmaxf(mx, wh2[i]);
#pragma unroll
  for (int off = 1; off < 64; off <<= 1) mx = fmaxf(mx, __shfl_xor(mx, off));
  __shared__ float sm[4];
  if ((t & 63) == 0) sm[t >> 6] = mx;
  __syncthreads();
  float M2 = fmaxf(fmaxf(sm[0], sm[1]), fmaxf(sm[2], sm[3]));
  const float L = 1.4426950408889634f;
  int i = blockIdx.x * 256 + t;
  float w1 = wh1[i], w2 = wh2[i];
  float m = lrelu(w1 + M2);
  e1p[i] = exp2f((w1 - m) * L);
  e1n[i] = exp2f((0.2f * w1 - m) * L);
  thr[i] = exp2f(-w1 * L);
  e2p[i] = exp2f(w2 * L);
  e2n[i] = exp2f(0.2f * w2 * L);
}

// ---- fused masked-softmax + PV (R9 verbatim, the 155.8 config's attn).
// Wave = 32 rows x 256 cols x 1024-j strip; masks wave-private in LDS;
// B staged via LDS dbuf (reg-split, XOR swizzle), one barrier/step;
// exp-free genP from tables. acc[8] f32x16 = 128 AGPR. Grid 64rb x 8js.
__launch_bounds__(256, 2)
__global__ void k_attn(const u64* __restrict__ maskG, const f16* __restrict__ whT16,
                       const float* __restrict__ e1pA, const float* __restrict__ e1nA,
                       const float* __restrict__ thrA, const float* __restrict__ e2pA,
                       const float* __restrict__ e2nA, f16* __restrict__ accP,
                       float* __restrict__ zP) {
  int bx = blockIdx.x;
  int js = bx & (JS - 1), rb = bx >> 3;
  int i0b = rb * 128;
  int jbase = js * STRIP;
  int tid = threadIdx.x, w = tid >> 6, l = tid & 63;
  int lr = l & 31, hi = l >> 5;
  int row = i0b + w * 32 + lr;

  __shared__ u64 mrow[4][32][18];
  __shared__ __align__(16) char ldsB[2][16384];

  // stage this wave's 32 rows x 16 mask words (wave-private, in-order DS)
#pragma unroll
  for (int p = 0; p < 4; ++p) {
    int r = 8 * p + (l >> 3);
    const i32x4* src =
        (const i32x4*)(maskG + (size_t)(i0b + 32 * w + r) * 128 + js * 16) + (l & 7);
    *(i32x4*)(&mrow[w][r][(l & 7) * 2]) = *src;
  }

  float E1p = e1pA[row], E1n = e1nA[row], T = thrA[row];
  f32x16 acc[8] = {};
  float za = 0.f;

  const size_t jb16 = (size_t)(jbase >> 4) * 4096;  // f16 offset of strip
  const float* e2pb = e2pA + jbase + 8 * hi;
  const float* e2nb = e2nA + jbase + 8 * hi;

  // staging map: granule g (16B) -> tile kb=g>>9, src f16 off 8*(g&511),
  // lds byte = kb*8192 + (16*(g&511)) ^ (((g>>3)&7)<<4)   [swizzle]
  int ldst[4];
  size_t gsrc[4];
#pragma unroll
  for (int r = 0; r < 4; ++r) {
    int g = r * 256 + tid;
    gsrc[r] = (size_t)(g >> 9) * 4096 + 8 * (g & 511);
    ldst[r] = (g >> 9) * 8192 + ((16 * (g & 511)) ^ (((g >> 3) & 7) << 4));
  }
  // per-lane conflict-free read base: (row,slot) bijective per 128B row
  int rdbase = (lr * 32 + hi * 16) ^ (((lr >> 2) & 7) << 4);

  i32x4 stg[4];
  // prologue: stage B(0)
#pragma unroll
  for (int r = 0; r < 4; ++r)
    stg[r] = __builtin_nontemporal_load((const i32x4*)(whT16 + jb16 + gsrc[r]));
#pragma unroll
  for (int r = 0; r < 4; ++r) *(i32x4*)(&ldsB[0][ldst[r]]) = stg[r];
  __syncthreads();

#pragma unroll 1
  for (int ch = 0; ch < 4; ++ch) {
    u64 wr0[4];
#pragma unroll
    for (int q = 0; q < 4; ++q) wr0[q] = mrow[w][lr][ch * 4 + q];
#pragma unroll 1
    for (int ts = 0; ts < 8; ++ts) {
      int t = ch * 8 + ts;
      int cur = t & 1;
      int jc = t * 32;
      // issue B(t+1) global loads (latency hides under genP + MFMA)
      if (t + 1 < NSTEP) {
        const f16* src = whT16 + jb16 + (size_t)(2 * (t + 1)) * 4096;
#pragma unroll
        for (int r = 0; r < 4; ++r)
          stg[r] = __builtin_nontemporal_load((const i32x4*)(src + gsrc[r]));
      }
      // genP: 16 P/lane, exp-free (bit lbit of word e <-> j=..+4*lbit+e)
      int sb = ts * 8 + 2 * hi;
      unsigned b4[4];
#pragma unroll
      for (int e = 0; e < 4; ++e) b4[e] = (unsigned)(wr0[e] >> sb);
      f16x8 pa0, pa1;
#pragma unroll
      for (int q = 0; q < 2; ++q) {
        int fo = jc + 4 * q;
        f32x4 ep0 = *(const f32x4*)(e2pb + fo);
        f32x4 en0 = *(const f32x4*)(e2nb + fo);
        f32x4 ep1 = *(const f32x4*)(e2pb + fo + 16);
        f32x4 en1 = *(const f32x4*)(e2nb + fo + 16);
#pragma unroll
        for (int e = 0; e < 4; ++e) {
          int f = 4 * q + e;
          bool s0 = ep0[e] >= T;
          float v0 = (s0 ? E1p : E1n) * (s0 ? ep0[e] : en0[e]);
          v0 = ((b4[e] >> q) & 1u) ? v0 : 0.f;
          za += v0;
          pa0[f] = (f16)v0;
          bool s1 = ep1[e] >= T;
          float v1 = (s1 ? E1p : E1n) * (s1 ? ep1[e] : en1[e]);
          v1 = ((b4[e] >> (4 + q)) & 1u) ? v1 : 0.f;
          za += v1;
          pa1[f] = (f16)v1;
        }
      }
      // MFMA from LDS (conflict-free swizzled reads)
#pragma unroll
      for (int cf = 0; cf < 8; ++cf) {
        f16x8 bf0 = *(const f16x8*)(&ldsB[cur][cf * 1024 + rdbase]);
        acc[cf] = __builtin_amdgcn_mfma_f32_32x32x16_f16(pa0, bf0, acc[cf], 0, 0, 0);
      }
#pragma unroll
      for (int cf = 0; cf < 8; ++cf) {
        f16x8 bf1 = *(const f16x8*)(&ldsB[cur][8192 + cf * 1024 + rdbase]);
        acc[cf] = __builtin_amdgcn_mfma_f32_32x32x16_f16(pa1, bf1, acc[cf], 0, 0, 0);
      }
      // write B(t+1) into the other buffer, one barrier per step
      if (t + 1 < NSTEP) {
#pragma unroll
        for (int r = 0; r < 4; ++r) *(i32x4*)(&ldsB[cur ^ 1][ldst[r]]) = stg[r];
        __syncthreads();
      }
    }
  }

  // Z: hi=0/1 lanes hold complementary j-slots of row
  za += __shfl_xor(za, 32);
  if (hi == 0) zP[(size_t)js * NN + row] = za;

  // partial accumulator out, f16 NT. C/D: col=lane&31, row=(r&3)+8*(r>>2)+4*hi
  f16* ap = accP + (size_t)js * NN * FOUT;
#pragma unroll
  for (int c = 0; c < 8; ++c)
#pragma unroll
    for (int r = 0; r < 16; ++r) {
      int grow = i0b + 32 * w + (r & 3) + 8 * (r >> 2) + 4 * hi;
      int gcol = c * 32 + lr;
      __builtin_nontemporal_store((f16)acc[c][r], ap + (size_t)grow * FOUT + gcol);
    }
}

// ---- combine JS f16 partials, divide by Z, elu
__global__ void k_combine(const f16* __restrict__ accP, const float* __restrict__ zP,
                          float* __restrict__ out) {
  int id = blockIdx.x * 256 + threadIdx.x;
  size_t idx = (size_t)id * 4;
  int row = (int)(idx >> 8);
  f32x4 s = {};
#pragma unroll
  for (int p = 0; p < JS; ++p) {
    f16x4 v = *(const f16x4*)(accP + (size_t)p * NN * FOUT + idx);
#pragma unroll
    for (int i = 0; i < 4; ++i) s[i] += (float)v[i];
  }
  float z = 0.f;
#pragma unroll
  for (int p = 0; p < JS; ++p) z += zP[(size_t)p * NN + row];
  float inv = (z > 0.f) ? 1.f / z : 0.f;
  f32x4 o;
#pragma unroll
  for (int i = 0; i < 4; ++i) {
    float x = s[i] * inv;
    o[i] = (x > 0.f) ? x : expm1f(x);
  }
  *(f32x4*)(out + idx) = o;
}

extern "C" void kernel_launch(void* const* d_in, const int* in_sizes, int n_in,
                              void* d_out, int out_size, void* d_ws, size_t ws_size,
                              hipStream_t stream) {
  const float* h = (const float*)d_in[0];
  const int* adj = (const int*)d_in[1];
  const float* W = (const float*)d_in[2];
  const float* a = (const float*)d_in[3];
  (void)in_sizes; (void)n_in; (void)out_size; (void)ws_size;

  char* ws = (char*)d_ws;
  size_t off = 0;
  auto alloc = [&](size_t bytes) {
    void* p = ws + off;
    off = (off + bytes + 255) & ~(size_t)255;
    return p;
  };
  f16* accP = (f16*)alloc((size_t)JS * NN * FOUT * 2);  // 32 MB
  u64* maskG = (u64*)alloc((size_t)NN * 128 * 8);       // 8 MB
  f16* whT16 = (f16*)alloc((size_t)FOUT * NN * 2);      // 4 MB
  f16* wth = (f16*)alloc((size_t)FOUT * FIN * 2);
  f16* wtl = (f16*)alloc((size_t)FOUT * FIN * 2);
  float* wh1 = (float*)alloc((size_t)NN * 4);
  float* wh2 = (float*)alloc((size_t)NN * 4);
  float* e1p = (float*)alloc((size_t)NN * 4);
  float* e1n = (float*)alloc((size_t)NN * 4);
  float* thr = (float*)alloc((size_t)NN * 4);
  float* e2p = (float*)alloc((size_t)NN * 4);
  float* e2n = (float*)alloc((size_t)NN * 4);
  float* zP = (float*)alloc((size_t)JS * NN * 4);

  k_prep_w<<<FIN * FOUT / 256, 256, 0, stream>>>(W, wth, wtl);
  k_fused<<<NN / 32 + NN / 4, 256, 0, stream>>>(adj, maskG, h, wth, wtl, a,
                                                whT16, wh1, wh2);
  k_maxprep<<<NN / 256, 256, 0, stream>>>(wh1, wh2, e1p, e1n, thr, e2p, e2n);
  k_attn<<<(NN / 128) * JS, 256, 0, stream>>>(maskG, whT16, e1p, e1n, thr, e2p, e2n,
                                              accP, zP);
  k_combine<<<NN * FOUT / 1024, 256, 0, stream>>>(accP, zP, (float*)d_out);
}

// Round 14
// 152.866 us; speedup vs baseline: 2.0718x; 1.2010x over previous
//
#include <hip/hip_runtime.h>

#define NN 8192
#define FIN 512
#define FOUT 256
#define JS 8
#define STRIP 1024
#define NSTEP 32

typedef _Float16 f16;
typedef __attribute__((ext_vector_type(8))) _Float16 f16x8;
typedef __attribute__((ext_vector_type(4))) _Float16 f16x4;
typedef __attribute__((ext_vector_type(4))) float f32x4;
typedef __attribute__((ext_vector_type(16))) float f32x16;
typedef __attribute__((ext_vector_type(4))) int i32x4;
typedef unsigned long long u64;

__device__ __forceinline__ float lrelu(float x) { return fmaxf(x, 0.2f * x); }

// ---- convert + prep_w, heterogeneous but occupancy-UNcoupled (both
// branches: no LDS, no launch_bounds, low VGPR -> full 32-wave occupancy).
// Blocks [0, NN/4): adj row -> bitmask via ballot (R9 verbatim, depth-4
// prefetch). Blocks [NN/4, NN/4+512): W f32 -> f16 hi/lo transpose.
__global__ void k_cvtprep(const int* __restrict__ adj, u64* __restrict__ maskG,
                          const float* __restrict__ W, f16* __restrict__ wth,
                          f16* __restrict__ wtl) {
  int bid = blockIdx.x;
  int tid = threadIdx.x;
  if (bid < NN / 4) {
    // convert: wave = one adj row; bit l of word (row*128+p*4+e) <-> j=p*256+4l+e
    int gw = bid * 4 + (tid >> 6);
    int l = tid & 63;
    const int* src = adj + (size_t)gw * NN + 4 * l;
    u64* dst = maskG + (size_t)gw * 128;
    i32x4 v[4];
#pragma unroll
    for (int p = 0; p < 4; ++p)
      v[p] = __builtin_nontemporal_load((const i32x4*)(src + p * 256));
#pragma unroll 1
    for (int p = 0; p < 32; ++p) {
      i32x4 cur = v[p & 3];
      u64 b0 = __ballot(cur[0] > 0);
      u64 b1 = __ballot(cur[1] > 0);
      u64 b2 = __ballot(cur[2] > 0);
      u64 b3 = __ballot(cur[3] > 0);
      if (p + 4 < 32)
        v[p & 3] = __builtin_nontemporal_load((const i32x4*)(src + (p + 4) * 256));
      if (l < 4) {
        u64 bb = (l == 0) ? b0 : (l == 1) ? b1 : (l == 2) ? b2 : b3;
        dst[p * 4 + l] = bb;
      }
    }
  } else {
    // prep W: f32 [FIN][FOUT] -> f16 hi/lo transposed [FOUT][FIN]
    int id = (bid - NN / 4) * 256 + tid;
    int c = id >> 9, k = id & 511;
    float v = W[k * FOUT + c];
    f16 a = (f16)v;
    wth[c * FIN + k] = a;
    wtl[c * FIN + k] = (f16)(v - (float)a);
  }
}

// ---- GEMM1 (R9 verbatim): Wh = h @ W via split-f16 MFMA; h converted
// in-reg. Emits whT16 (f16, tiled [j/16][256 c][16 j]), Wh1, Wh2 (f32).
__launch_bounds__(256, 2)
__global__ void k_gemm1(const float* __restrict__ h, const f16* __restrict__ wth,
                        const f16* __restrict__ wtl, const float* __restrict__ avec,
                        f16* __restrict__ whT16, float* __restrict__ wh1,
                        float* __restrict__ wh2) {
  int i0 = blockIdx.x * 32;
  int tid = threadIdx.x;
  int w = tid >> 6, l = tid & 63, m = l & 15, g = l >> 4;
  f32x4 acc[2][4] = {};
#pragma unroll 1
  for (int k0 = 0; k0 < FIN; k0 += 32) {
    f16x8 ah[2], al[2], bh[4], bl[4];
#pragma unroll
    for (int rf = 0; rf < 2; ++rf) {
      int ro = (i0 + 16 * rf + m) * FIN + k0 + 8 * g;
      f32x4 va = *(const f32x4*)(h + ro);
      f32x4 vb = *(const f32x4*)(h + ro + 4);
#pragma unroll
      for (int e = 0; e < 4; ++e) {
        f16 x = (f16)va[e];
        ah[rf][e] = x;
        al[rf][e] = (f16)(va[e] - (float)x);
        f16 y = (f16)vb[e];
        ah[rf][4 + e] = y;
        al[rf][4 + e] = (f16)(vb[e] - (float)y);
      }
    }
#pragma unroll
    for (int cf = 0; cf < 4; ++cf) {
      int co = (64 * w + 16 * cf + m) * FIN + k0 + 8 * g;
      bh[cf] = *(const f16x8*)(wth + co);
      bl[cf] = *(const f16x8*)(wtl + co);
    }
#pragma unroll
    for (int rf = 0; rf < 2; ++rf)
#pragma unroll
      for (int cf = 0; cf < 4; ++cf) {
        acc[rf][cf] = __builtin_amdgcn_mfma_f32_16x16x32_f16(ah[rf], bh[cf], acc[rf][cf], 0, 0, 0);
        acc[rf][cf] = __builtin_amdgcn_mfma_f32_16x16x32_f16(ah[rf], bl[cf], acc[rf][cf], 0, 0, 0);
        acc[rf][cf] = __builtin_amdgcn_mfma_f32_16x16x32_f16(al[rf], bh[cf], acc[rf][cf], 0, 0, 0);
      }
  }
  __shared__ float tile[32][FOUT + 1];
#pragma unroll
  for (int rf = 0; rf < 2; ++rf)
#pragma unroll
    for (int cf = 0; cf < 4; ++cf)
#pragma unroll
      for (int r = 0; r < 4; ++r)
        tile[16 * rf + 4 * g + r][64 * w + 16 * cf + m] = acc[rf][cf][r];
  __syncthreads();
  {  // whT16 tiled write: thread = column c, 32 rows = 2 j16-groups
    int c = tid;
    f16x8 vv[4];
#pragma unroll
    for (int r = 0; r < 32; ++r) vv[r >> 3][r & 7] = (f16)tile[r][c];
    size_t base = ((size_t)(i0 >> 4) * 256 + c) * 16;
    *(f16x8*)(whT16 + base) = vv[0];
    *(f16x8*)(whT16 + base + 8) = vv[1];
    *(f16x8*)(whT16 + base + 4096) = vv[2];
    *(f16x8*)(whT16 + base + 4096 + 8) = vv[3];
  }
  {  // Wh1/Wh2 row dots: 8 lanes per row
    int r = tid >> 3, ls = tid & 7;
    float s1 = 0.f, s2 = 0.f;
    for (int c = ls; c < FOUT; c += 8) {
      float v = tile[r][c];
      s1 = fmaf(v, avec[c], s1);
      s2 = fmaf(v, avec[FOUT + c], s2);
    }
#pragma unroll
    for (int off = 1; off < 8; off <<= 1) {
      s1 += __shfl_xor(s1, off);
      s2 += __shfl_xor(s2, off);
    }
    if (ls == 0) {
      wh1[i0 + r] = s1;
      wh2[i0 + r] = s2;
    }
  }
}

// ---- merged: global max of Wh2 + per-row/per-col exp factor tables.
__global__ void k_maxprep(const float* __restrict__ wh1, const float* __restrict__ wh2,
                          float* __restrict__ e1p, float* __restrict__ e1n,
                          float* __restrict__ thr, float* __restrict__ e2p,
                          float* __restrict__ e2n) {
  int t = threadIdx.x;
  float mx = -1e30f;
  for (int i = t; i < NN; i += 256) mx = fmaxf(mx, wh2[i]);
#pragma unroll
  for (int off = 1; off < 64; off <<= 1) mx = fmaxf(mx, __shfl_xor(mx, off));
  __shared__ float sm[4];
  if ((t & 63) == 0) sm[t >> 6] = mx;
  __syncthreads();
  float M2 = fmaxf(fmaxf(sm[0], sm[1]), fmaxf(sm[2], sm[3]));
  const float L = 1.4426950408889634f;
  int i = blockIdx.x * 256 + t;
  float w1 = wh1[i], w2 = wh2[i];
  float m = lrelu(w1 + M2);
  e1p[i] = exp2f((w1 - m) * L);
  e1n[i] = exp2f((0.2f * w1 - m) * L);
  thr[i] = exp2f(-w1 * L);
  e2p[i] = exp2f(w2 * L);
  e2n[i] = exp2f(0.2f * w2 * L);
}

// ---- fused masked-softmax + PV (R9 verbatim, the 155.8 config's attn).
// Wave = 32 rows x 256 cols x 1024-j strip; masks wave-private in LDS;
// B staged via LDS dbuf (reg-split, XOR swizzle), one barrier/step;
// exp-free genP from tables. acc[8] f32x16 = 128 AGPR. Grid 64rb x 8js.
__launch_bounds__(256, 2)
__global__ void k_attn(const u64* __restrict__ maskG, const f16* __restrict__ whT16,
                       const float* __restrict__ e1pA, const float* __restrict__ e1nA,
                       const float* __restrict__ thrA, const float* __restrict__ e2pA,
                       const float* __restrict__ e2nA, f16* __restrict__ accP,
                       float* __restrict__ zP) {
  int bx = blockIdx.x;
  int js = bx & (JS - 1), rb = bx >> 3;
  int i0b = rb * 128;
  int jbase = js * STRIP;
  int tid = threadIdx.x, w = tid >> 6, l = tid & 63;
  int lr = l & 31, hi = l >> 5;
  int row = i0b + w * 32 + lr;

  __shared__ u64 mrow[4][32][18];
  __shared__ __align__(16) char ldsB[2][16384];

  // stage this wave's 32 rows x 16 mask words (wave-private, in-order DS)
#pragma unroll
  for (int p = 0; p < 4; ++p) {
    int r = 8 * p + (l >> 3);
    const i32x4* src =
        (const i32x4*)(maskG + (size_t)(i0b + 32 * w + r) * 128 + js * 16) + (l & 7);
    *(i32x4*)(&mrow[w][r][(l & 7) * 2]) = *src;
  }

  float E1p = e1pA[row], E1n = e1nA[row], T = thrA[row];
  f32x16 acc[8] = {};
  float za = 0.f;

  const size_t jb16 = (size_t)(jbase >> 4) * 4096;  // f16 offset of strip
  const float* e2pb = e2pA + jbase + 8 * hi;
  const float* e2nb = e2nA + jbase + 8 * hi;

  // staging map: granule g (16B) -> tile kb=g>>9, src f16 off 8*(g&511),
  // lds byte = kb*8192 + (16*(g&511)) ^ (((g>>3)&7)<<4)   [swizzle]
  int ldst[4];
  size_t gsrc[4];
#pragma unroll
  for (int r = 0; r < 4; ++r) {
    int g = r * 256 + tid;
    gsrc[r] = (size_t)(g >> 9) * 4096 + 8 * (g & 511);
    ldst[r] = (g >> 9) * 8192 + ((16 * (g & 511)) ^ (((g >> 3) & 7) << 4));
  }
  // per-lane conflict-free read base: (row,slot) bijective per 128B row
  int rdbase = (lr * 32 + hi * 16) ^ (((lr >> 2) & 7) << 4);

  i32x4 stg[4];
  // prologue: stage B(0)
#pragma unroll
  for (int r = 0; r < 4; ++r)
    stg[r] = __builtin_nontemporal_load((const i32x4*)(whT16 + jb16 + gsrc[r]));
#pragma unroll
  for (int r = 0; r < 4; ++r) *(i32x4*)(&ldsB[0][ldst[r]]) = stg[r];
  __syncthreads();

#pragma unroll 1
  for (int ch = 0; ch < 4; ++ch) {
    u64 wr0[4];
#pragma unroll
    for (int q = 0; q < 4; ++q) wr0[q] = mrow[w][lr][ch * 4 + q];
#pragma unroll 1
    for (int ts = 0; ts < 8; ++ts) {
      int t = ch * 8 + ts;
      int cur = t & 1;
      int jc = t * 32;
      // issue B(t+1) global loads (latency hides under genP + MFMA)
      if (t + 1 < NSTEP) {
        const f16* src = whT16 + jb16 + (size_t)(2 * (t + 1)) * 4096;
#pragma unroll
        for (int r = 0; r < 4; ++r)
          stg[r] = __builtin_nontemporal_load((const i32x4*)(src + gsrc[r]));
      }
      // genP: 16 P/lane, exp-free (bit lbit of word e <-> j=..+4*lbit+e)
      int sb = ts * 8 + 2 * hi;
      unsigned b4[4];
#pragma unroll
      for (int e = 0; e < 4; ++e) b4[e] = (unsigned)(wr0[e] >> sb);
      f16x8 pa0, pa1;
#pragma unroll
      for (int q = 0; q < 2; ++q) {
        int fo = jc + 4 * q;
        f32x4 ep0 = *(const f32x4*)(e2pb + fo);
        f32x4 en0 = *(const f32x4*)(e2nb + fo);
        f32x4 ep1 = *(const f32x4*)(e2pb + fo + 16);
        f32x4 en1 = *(const f32x4*)(e2nb + fo + 16);
#pragma unroll
        for (int e = 0; e < 4; ++e) {
          int f = 4 * q + e;
          bool s0 = ep0[e] >= T;
          float v0 = (s0 ? E1p : E1n) * (s0 ? ep0[e] : en0[e]);
          v0 = ((b4[e] >> q) & 1u) ? v0 : 0.f;
          za += v0;
          pa0[f] = (f16)v0;
          bool s1 = ep1[e] >= T;
          float v1 = (s1 ? E1p : E1n) * (s1 ? ep1[e] : en1[e]);
          v1 = ((b4[e] >> (4 + q)) & 1u) ? v1 : 0.f;
          za += v1;
          pa1[f] = (f16)v1;
        }
      }
      // MFMA from LDS (conflict-free swizzled reads)
#pragma unroll
      for (int cf = 0; cf < 8; ++cf) {
        f16x8 bf0 = *(const f16x8*)(&ldsB[cur][cf * 1024 + rdbase]);
        acc[cf] = __builtin_amdgcn_mfma_f32_32x32x16_f16(pa0, bf0, acc[cf], 0, 0, 0);
      }
#pragma unroll
      for (int cf = 0; cf < 8; ++cf) {
        f16x8 bf1 = *(const f16x8*)(&ldsB[cur][8192 + cf * 1024 + rdbase]);
        acc[cf] = __builtin_amdgcn_mfma_f32_32x32x16_f16(pa1, bf1, acc[cf], 0, 0, 0);
      }
      // write B(t+1) into the other buffer, one barrier per step
      if (t + 1 < NSTEP) {
#pragma unroll
        for (int r = 0; r < 4; ++r) *(i32x4*)(&ldsB[cur ^ 1][ldst[r]]) = stg[r];
        __syncthreads();
      }
    }
  }

  // Z: hi=0/1 lanes hold complementary j-slots of row
  za += __shfl_xor(za, 32);
  if (hi == 0) zP[(size_t)js * NN + row] = za;

  // partial accumulator out, f16 NT. C/D: col=lane&31, row=(r&3)+8*(r>>2)+4*hi
  f16* ap = accP + (size_t)js * NN * FOUT;
#pragma unroll
  for (int c = 0; c < 8; ++c)
#pragma unroll
    for (int r = 0; r < 16; ++r) {
      int grow = i0b + 32 * w + (r & 3) + 8 * (r >> 2) + 4 * hi;
      int gcol = c * 32 + lr;
      __builtin_nontemporal_store((f16)acc[c][r], ap + (size_t)grow * FOUT + gcol);
    }
}

// ---- combine JS f16 partials, divide by Z, elu. f16x8 loads (16 B/lane).
__global__ void k_combine(const f16* __restrict__ accP, const float* __restrict__ zP,
                          float* __restrict__ out) {
  int id = blockIdx.x * 256 + threadIdx.x;
  size_t idx = (size_t)id * 8;
  int row = (int)(idx >> 8);
  float s[8] = {};
#pragma unroll
  for (int p = 0; p < JS; ++p) {
    f16x8 v = *(const f16x8*)(accP + (size_t)p * NN * FOUT + idx);
#pragma unroll
    for (int i = 0; i < 8; ++i) s[i] += (float)v[i];
  }
  float z = 0.f;
#pragma unroll
  for (int p = 0; p < JS; ++p) z += zP[(size_t)p * NN + row];
  float inv = (z > 0.f) ? 1.f / z : 0.f;
  f32x4 o0, o1;
#pragma unroll
  for (int i = 0; i < 4; ++i) {
    float x0 = s[i] * inv;
    o0[i] = (x0 > 0.f) ? x0 : expm1f(x0);
    float x1 = s[4 + i] * inv;
    o1[i] = (x1 > 0.f) ? x1 : expm1f(x1);
  }
  *(f32x4*)(out + idx) = o0;
  *(f32x4*)(out + idx + 4) = o1;
}

extern "C" void kernel_launch(void* const* d_in, const int* in_sizes, int n_in,
                              void* d_out, int out_size, void* d_ws, size_t ws_size,
                              hipStream_t stream) {
  const float* h = (const float*)d_in[0];
  const int* adj = (const int*)d_in[1];
  const float* W = (const float*)d_in[2];
  const float* a = (const float*)d_in[3];
  (void)in_sizes; (void)n_in; (void)out_size; (void)ws_size;

  char* ws = (char*)d_ws;
  size_t off = 0;
  auto alloc = [&](size_t bytes) {
    void* p = ws + off;
    off = (off + bytes + 255) & ~(size_t)255;
    return p;
  };
  f16* accP = (f16*)alloc((size_t)JS * NN * FOUT * 2);  // 32 MB
  u64* maskG = (u64*)alloc((size_t)NN * 128 * 8);       // 8 MB
  f16* whT16 = (f16*)alloc((size_t)FOUT * NN * 2);      // 4 MB
  f16* wth = (f16*)alloc((size_t)FOUT * FIN * 2);
  f16* wtl = (f16*)alloc((size_t)FOUT * FIN * 2);
  float* wh1 = (float*)alloc((size_t)NN * 4);
  float* wh2 = (float*)alloc((size_t)NN * 4);
  float* e1p = (float*)alloc((size_t)NN * 4);
  float* e1n = (float*)alloc((size_t)NN * 4);
  float* thr = (float*)alloc((size_t)NN * 4);
  float* e2p = (float*)alloc((size_t)NN * 4);
  float* e2n = (float*)alloc((size_t)NN * 4);
  float* zP = (float*)alloc((size_t)JS * NN * 4);

  k_cvtprep<<<NN / 4 + FIN * FOUT / 256, 256, 0, stream>>>(adj, maskG, W, wth, wtl);
  k_gemm1<<<NN / 32, 256, 0, stream>>>(h, wth, wtl, a, whT16, wh1, wh2);
  k_maxprep<<<NN / 256, 256, 0, stream>>>(wh1, wh2, e1p, e1n, thr, e2p, e2n);
  k_attn<<<(NN / 128) * JS, 256, 0, stream>>>(maskG, whT16, e1p, e1n, thr, e2p, e2n,
                                              accP, zP);
  k_combine<<<NN * FOUT / 2048, 256, 0, stream>>>(accP, zP, (float*)d_out);
}